// Round 1
// baseline (87.443 us; speedup 1.0000x reference)
//
#include <hip/hip_runtime.h>
#include <math.h>

// Problem constants (from reference):
//   input  x: (B=16, C=32, H=256, W=256) fp32
//   kernel k: (OC=32, 5, 5) fp32
//   out:      (B=16, OC=32, H=256, W=256) fp32
//   out[b,oc,y,x] = max_{dy,dx} min(xmax[b, y+dy-2, x+dx-2], k[oc,dy,dx])
//   where xmax = max over channel axis, OOB patch values = -inf.

#define BATCH 16
#define CH    32
#define OCH   32
#define HH    256
#define WW    256
#define HWSZ  (HH * WW)          // 65536

// ---------------- Pass 1: channel max, float4 vectorized ----------------
// 16*256*256/4 = 262144 float4s. 128 MB read, 4 MB write. Memory-bound.
__global__ __launch_bounds__(256) void chanmax_kernel(const float* __restrict__ x,
                                                      float* __restrict__ xm) {
    int i4 = blockIdx.x * blockDim.x + threadIdx.x;   // 0 .. 262143
    int b  = i4 >> 14;                                // / (HWSZ/4)
    int r  = i4 & 16383;
    const float4* base = (const float4*)x + (size_t)b * CH * (HWSZ / 4) + r;
    float4 m = base[0];
#pragma unroll
    for (int c = 1; c < CH; ++c) {
        float4 v = base[(size_t)c * (HWSZ / 4)];
        m.x = fmaxf(m.x, v.x);
        m.y = fmaxf(m.y, v.y);
        m.z = fmaxf(m.z, v.z);
        m.w = fmaxf(m.w, v.w);
    }
    ((float4*)xm)[i4] = m;
}

// ---------------- Pass 2: 5x5 maxmin "conv" ----------------
// One thread = 4 consecutive x positions (float4 stores), all 32 oc.
// Patch (5 rows x 8 cols) kept in VGPRs, reused across the 32 oc.
// Kernel taps are wave-uniform -> scalar loads.
__global__ __launch_bounds__(256) void maxmin_conv_kernel(const float* __restrict__ xm,
                                                          const float* __restrict__ kk,
                                                          float* __restrict__ out) {
    int t  = blockIdx.x * blockDim.x + threadIdx.x;   // 0 .. 262143
    int x0 = (t & 63) << 2;                           // 0,4,...,252
    int y  = (t >> 6) & 255;
    int b  = t >> 14;

    const float NI = -INFINITY;

    // Load 5x8 patch into registers (clamped addresses, select -inf for OOB).
    float p[40];
#pragma unroll
    for (int dy = 0; dy < 5; ++dy) {
        int yy  = y + dy - 2;
        bool rv = (yy >= 0) && (yy < HH);
        int yc  = yy < 0 ? 0 : (yy > HH - 1 ? HH - 1 : yy);
        const float* row = xm + ((size_t)b * HH + yc) * WW;
#pragma unroll
        for (int dx = 0; dx < 8; ++dx) {
            int xx  = x0 + dx - 2;
            bool cv = (xx >= 0) && (xx < WW);
            int xc  = xx < 0 ? 0 : (xx > WW - 1 ? WW - 1 : xx);
            float v = row[xc];
            p[dy * 8 + dx] = (rv && cv) ? v : NI;
        }
    }

    size_t obase = (size_t)b * OCH * HWSZ + (size_t)y * WW + x0;

    for (int oc = 0; oc < OCH; ++oc) {
        const float* kv = kk + oc * 25;
        float kr[25];
#pragma unroll
        for (int i = 0; i < 25; ++i) kr[i] = kv[i];   // uniform -> s_load

        float a0 = NI, a1 = NI, a2 = NI, a3 = NI;
#pragma unroll
        for (int dy = 0; dy < 5; ++dy) {
#pragma unroll
            for (int dx = 0; dx < 5; ++dx) {
                float kw = kr[dy * 5 + dx];
                int   pi = dy * 8 + dx;
                a0 = fmaxf(a0, fminf(p[pi + 0], kw));
                a1 = fmaxf(a1, fminf(p[pi + 1], kw));
                a2 = fmaxf(a2, fminf(p[pi + 2], kw));
                a3 = fmaxf(a3, fminf(p[pi + 3], kw));
            }
        }
        float4 o = make_float4(a0, a1, a2, a3);
        *(float4*)(out + obase + (size_t)oc * HWSZ) = o;
    }
}

extern "C" void kernel_launch(void* const* d_in, const int* in_sizes, int n_in,
                              void* d_out, int out_size, void* d_ws, size_t ws_size,
                              hipStream_t stream) {
    const float* x  = (const float*)d_in[0];
    const float* kk = (const float*)d_in[1];
    float* out      = (float*)d_out;
    float* xm       = (float*)d_ws;   // needs 16*256*256*4 = 4 MB scratch

    // Pass 1: channel max -> xm
    chanmax_kernel<<<BATCH * HWSZ / 4 / 256, 256, 0, stream>>>(x, xm);
    // Pass 2: maxmin conv -> out
    maxmin_conv_kernel<<<BATCH * HWSZ / 4 / 256, 256, 0, stream>>>(xm, kk, out);
}

// Round 2
// 80.733 us; speedup vs baseline: 1.0831x; 1.0831x over previous
//
#include <hip/hip_runtime.h>
#include <math.h>

// out[b,oc,y,x] = max_{dy,dx} min(xmax[b, y+dy-2, x+dx-2], k[oc,dy,dx])
// xmax = max over C=32 input channels; OOB patch values = -inf.
// Shapes: x (16,32,256,256) f32, k (32,5,5) f32, out (16,32,256,256) f32.

#define BATCH 16
#define CH    32
#define OCH   32
#define HH    256
#define WW    256
#define HWSZ  (HH * WW)          // 65536

// ---------------- Pass 1: channel max, float4 vectorized ----------------
__global__ __launch_bounds__(256) void chanmax_kernel(const float* __restrict__ x,
                                                      float* __restrict__ xm) {
    int i4 = blockIdx.x * blockDim.x + threadIdx.x;   // 0 .. 262143
    int b  = i4 >> 14;
    int r  = i4 & 16383;
    const float4* base = (const float4*)x + (size_t)b * CH * (HWSZ / 4) + r;
    float4 m = base[0];
#pragma unroll
    for (int c = 1; c < CH; ++c) {
        float4 v = base[(size_t)c * (HWSZ / 4)];
        m.x = fmaxf(m.x, v.x);
        m.y = fmaxf(m.y, v.y);
        m.z = fmaxf(m.z, v.z);
        m.w = fmaxf(m.w, v.w);
    }
    ((float4*)xm)[i4] = m;
}

// ---------------- Pass 2: 5x5 maxmin "conv" ----------------
// One thread = 4 consecutive x positions x 16 output channels.
// 25 independent v_min_f32 + 12-op v_max3_f32 tree per (px, oc).
__device__ __forceinline__ float vmax3(float a, float b, float c) {
    float d;
    asm("v_max3_f32 %0, %1, %2, %3" : "=v"(d) : "v"(a), "v"(b), "v"(c));
    return d;
}

__global__ __launch_bounds__(256) void maxmin_conv_kernel(const float* __restrict__ xm,
                                                          const float* __restrict__ kk,
                                                          float* __restrict__ out) {
    int bid  = blockIdx.x;
    int half = bid & 1;                                   // oc 0-15 or 16-31
    int t    = (bid >> 1) * blockDim.x + threadIdx.x;     // 0 .. 262143
    int x0 = (t & 63) << 2;                               // 0,4,...,252
    int y  = (t >> 6) & 255;
    int b  = t >> 14;

    const float NI = -INFINITY;
    bool xlo = (x0 == 0);
    bool xhi = (x0 == 252);

    // 5x8 patch in registers. x-validity: dx<2 bad only if x0==0; dx>=6 bad
    // only if x0==252; dx in [2,5] always valid in x.
    float p[40];
#pragma unroll
    for (int dy = 0; dy < 5; ++dy) {
        int yy  = y + dy - 2;
        bool rv = (yy >= 0) && (yy < HH);
        int yc  = yy < 0 ? 0 : (yy > HH - 1 ? HH - 1 : yy);
        const float* row = xm + ((size_t)b * HH + yc) * WW;
#pragma unroll
        for (int dx = 0; dx < 8; ++dx) {
            int xx = x0 + dx - 2;
            int xc = xx < 0 ? 0 : (xx > WW - 1 ? WW - 1 : xx);
            float v = row[xc];
            bool valid = rv;
            if (dx < 2)  valid = valid && !xlo;
            if (dx >= 6) valid = valid && !xhi;
            p[dy * 8 + dx] = valid ? v : NI;
        }
    }

    const float* kbase = kk + half * 16 * 25;
    size_t obase = (size_t)b * OCH * HWSZ + (size_t)(half * 16) * HWSZ
                 + (size_t)y * WW + x0;

#pragma unroll 2
    for (int o = 0; o < 16; ++o) {
        const float* kv = kbase + o * 25;
        float kr[25];
#pragma unroll
        for (int i = 0; i < 25; ++i) kr[i] = kv[i];       // uniform -> s_load

        float a[4];
#pragma unroll
        for (int j = 0; j < 4; ++j) {
            float m[25];
#pragma unroll
            for (int dy = 0; dy < 5; ++dy)
#pragma unroll
                for (int dx = 0; dx < 5; ++dx)
                    m[dy * 5 + dx] = fminf(p[dy * 8 + dx + j], kr[dy * 5 + dx]);
            float t0 = vmax3(m[0],  m[1],  m[2]);
            float t1 = vmax3(m[3],  m[4],  m[5]);
            float t2 = vmax3(m[6],  m[7],  m[8]);
            float t3 = vmax3(m[9],  m[10], m[11]);
            float t4 = vmax3(m[12], m[13], m[14]);
            float t5 = vmax3(m[15], m[16], m[17]);
            float t6 = vmax3(m[18], m[19], m[20]);
            float t7 = vmax3(m[21], m[22], m[23]);
            float u0 = vmax3(t0, t1, t2);
            float u1 = vmax3(t3, t4, t5);
            float u2 = vmax3(t6, t7, m[24]);
            a[j] = vmax3(u0, u1, u2);
        }
        *(float4*)(out + obase + (size_t)o * HWSZ) = make_float4(a[0], a[1], a[2], a[3]);
    }
}

extern "C" void kernel_launch(void* const* d_in, const int* in_sizes, int n_in,
                              void* d_out, int out_size, void* d_ws, size_t ws_size,
                              hipStream_t stream) {
    const float* x  = (const float*)d_in[0];
    const float* kk = (const float*)d_in[1];
    float* out      = (float*)d_out;
    float* xm       = (float*)d_ws;   // 16*256*256*4 = 4 MB scratch

    chanmax_kernel<<<BATCH * HWSZ / 4 / 256, 256, 0, stream>>>(x, xm);
    maxmin_conv_kernel<<<2 * BATCH * HWSZ / 4 / 256, 256, 0, stream>>>(xm, kk, out);
}